// Round 12
// baseline (5776.572 us; speedup 1.0000x reference)
//
#include <hip/hip_runtime.h>
#include <hip/hip_bf16.h>

#define Bsz 256
#define Nd  512
#define Hd  2048
#define Td  64
#define OFF_T (Bsz * Td * Nd)
#define OFF_L (OFF_T + Td)
#define LDU 514   // Ulds stride (elements)
#define LDZ 136   // Zlds stride

typedef __attribute__((ext_vector_type(8))) short short8;
typedef __attribute__((ext_vector_type(4))) float f32x4;
typedef __attribute__((ext_vector_type(4))) unsigned u32x4;

static __device__ __forceinline__ unsigned short f2bf(float x) {
  unsigned u = __builtin_bit_cast(unsigned, x);
  u += 0x7FFFu + ((u >> 16) & 1u);   // RNE
  return (unsigned short)(u >> 16);
}
static __device__ __forceinline__ float fast_tanh(float x) {
  float ex = __expf(2.0f * x);       // inf-safe
  return 1.0f - 2.0f / (ex + 1.0f);
}
// ---- agent-scope (sc1, LLC coherence point) primitives — the ONLY verified
// cross-block path on this part (live & correct rounds 3-6, 9-11).
static __device__ __forceinline__ unsigned long long lda64(const void* p) {
  return __hip_atomic_load((const unsigned long long*)p, __ATOMIC_RELAXED,
                           __HIP_MEMORY_SCOPE_AGENT);
}
static __device__ __forceinline__ void sta64(void* p, unsigned long long v) {
  __hip_atomic_store((unsigned long long*)p, v, __ATOMIC_RELAXED,
                     __HIP_MEMORY_SCOPE_AGENT);
}
static __device__ __forceinline__ unsigned long long tagf32(float x, unsigned tag) {
  return (unsigned long long)__builtin_bit_cast(unsigned, x) |
         ((unsigned long long)tag << 32);
}

// 256 blocks x 256 threads (4 waves), 1 block/CU (LDS-forced).
// pod g = blk & 15 (16 blocks, batch rows g*16..+16);
// il = blk >> 4: H-slice owner (GEMM1) / N-slice owner (GEMM2).
// Sync = generation-TAGGED data words: {payload, tag} in one atomic u64.
// No flags, no drains, no rotation — validity travels with the data (1 RT).
__launch_bounds__(256, 1)
__global__ void ode_tg(const float* __restrict__ y0g, const float* __restrict__ te,
                       const float* __restrict__ W1, const float* __restrict__ b1,
                       const float* __restrict__ W2, const float* __restrict__ b2,
                       float* __restrict__ out,
                       unsigned long long* __restrict__ kD,   // [pod][row16][col512]
                       unsigned long long* __restrict__ ZD) { // [pod][mem][row16][cp64]
  __shared__ unsigned short Ulds[16 * LDU];
  __shared__ unsigned short Zlds[16 * LDZ];
  __shared__ float red[4][16][33];
  __shared__ char spad[56 * 1024];   // occupancy limiter: 1 block/CU

  const int blk = blockIdx.x;
  const int g = blk & 15, il = blk >> 4;
  const int tid = threadIdx.x;
  const int wv = tid >> 6, lane = tid & 63;
  const int lr = lane & 15, lk = lane >> 4;

  if (te[0] == 1.0e30f) {            // never true; keeps spad allocated
    ((volatile char*)spad)[tid] = (char)tid;
    out[0] = ((volatile char*)spad)[0];
  }

  // ---------- one-time: resident weight fragments ----------
  short8 w1f[2][16];                 // W1 slice: cols il*128 + wv*32 + n*16 + lr
  {
    const int hbase = il * 128 + wv * 32;
    #pragma unroll
    for (int n = 0; n < 2; ++n) {
      const int col = hbase + n * 16 + lr;
      #pragma unroll
      for (int kt = 0; kt < 16; ++kt) {
        short8 v;
        #pragma unroll
        for (int jj = 0; jj < 8; ++jj)
          v[jj] = (short)f2bf(W1[(kt * 32 + lk * 8 + jj) * Hd + col]);
        w1f[n][kt] = v;
      }
    }
  }
  short8 w2f[2][16];                 // W2 slice: cols il*32 + n*16 + lr, K-chunk wv*512
  {
    #pragma unroll
    for (int n = 0; n < 2; ++n) {
      const int col = il * 32 + n * 16 + lr;
      #pragma unroll
      for (int kt = 0; kt < 16; ++kt) {
        short8 v;
        #pragma unroll
        for (int jj = 0; jj < 8; ++jj)
          v[jj] = (short)f2bf(W2[(wv * 512 + kt * 32 + lk * 8 + jj) * Nd + col]);
        w2f[n][kt] = v;
      }
    }
  }
  float b1c[2];
  b1c[0] = b1[il * 128 + wv * 32 + lr];
  b1c[1] = b1[il * 128 + wv * 32 + 16 + lr];

  // ---------- per-thread state mapping ----------
  const int r  = tid >> 4;           // local m-row 0..15
  const int cq = tid & 15;           // 32-col N chunk
  const int cb = cq * 32;
  const int rowg = g * 16 + r;
  const int c2 = (tid & 15) * 2;
  const int rowe = tid >> 4;
  const float b2e0 = b2[il * 32 + c2], b2e1 = b2[il * 32 + c2 + 1];

  unsigned long long* myK = &kD[((size_t)g * 16 + r) * 512 + cb];  // 32 words I consume

  float yv[32];
  #pragma unroll
  for (int gg = 0; gg < 8; ++gg) {
    f32x4 v = *(const f32x4*)&y0g[rowg * Nd + cb + gg * 4];
    yv[gg * 4 + 0] = v[0]; yv[gg * 4 + 1] = v[1];
    yv[gg * 4 + 2] = v[2]; yv[gg * 4 + 3] = v[3];
  }
  float acc_y[32];
  #pragma unroll
  for (int p = 0; p < 32; ++p) acc_y[p] = 0.0f;

  // ---------- pre-loop outputs ----------
  if (cq == il) {
    #pragma unroll
    for (int gg = 0; gg < 8; ++gg) {
      f32x4 v = {yv[gg * 4], yv[gg * 4 + 1], yv[gg * 4 + 2], yv[gg * 4 + 3]};
      *(f32x4*)&out[rowg * (Td * Nd) + cb + gg * 4] = v;
    }
  }
  if (blk == 0) {
    if (tid < Td) out[OFF_T + tid] = te[tid];
    out[OFF_L + tid] = 0.0f;
  }

  // ---------- main loop: 63 steps x 4 evals ----------
  int j = 0;
  for (int t = 0; t < Td - 1; ++t) {
    const float h = te[t + 1] - te[t];
    for (int e = 1; e <= 4; ++e) {
      // ---- consume k(j-1): tagged words, poll-until-tag==j (1 RT steady) ----
      float kv[32];
      if (!(e == 1 && t == 0)) {
        const unsigned tgt = (unsigned)j;   // eval j-1 posts tag j
        unsigned long long w[32];
        for (;;) {
          #pragma unroll
          for (int i = 0; i < 32; ++i) w[i] = lda64(myK + i);
          bool ok = true;
          #pragma unroll
          for (int i = 0; i < 32; ++i) ok &= ((unsigned)(w[i] >> 32) == tgt);
          if (__all((int)ok)) break;
          __builtin_amdgcn_s_sleep(1);
        }
        #pragma unroll
        for (int i = 0; i < 32; ++i)
          kv[i] = __builtin_bit_cast(float, (unsigned)w[i]);
      }
      // ---- U phase ----
      if (e == 1) {
        if (t > 0) {
          const float hp6 = (te[t] - te[t - 1]) * (1.0f / 6.0f);
          #pragma unroll
          for (int p2 = 0; p2 < 32; ++p2) yv[p2] += hp6 * (acc_y[p2] + kv[p2]);
          if (cq == il) {
            #pragma unroll
            for (int gg = 0; gg < 8; ++gg) {
              f32x4 v = {yv[gg * 4], yv[gg * 4 + 1], yv[gg * 4 + 2], yv[gg * 4 + 3]};
              *(f32x4*)&out[rowg * (Td * Nd) + t * Nd + cb + gg * 4] = v;
            }
          }
        }
        #pragma unroll
        for (int p2 = 0; p2 < 32; ++p2) acc_y[p2] = 0.0f;
        #pragma unroll
        for (int gg = 0; gg < 4; ++gg) {
          short8 s;
          #pragma unroll
          for (int p2 = 0; p2 < 8; ++p2) s[p2] = (short)f2bf(yv[gg * 8 + p2]);
          *(short8*)&Ulds[r * LDU + cb + gg * 8] = s;
        }
      } else {
        const float c = (e == 4) ? h : 0.5f * h;
        const float w = (e == 2) ? 1.0f : 2.0f;
        #pragma unroll
        for (int gg = 0; gg < 4; ++gg) {
          short8 s;
          #pragma unroll
          for (int p2 = 0; p2 < 8; ++p2) {
            const int idx = gg * 8 + p2;
            acc_y[idx] += w * kv[idx];
            s[p2] = (short)f2bf(yv[idx] + c * kv[idx]);
          }
          *(short8*)&Ulds[r * LDU + cb + gg * 8] = s;
        }
      }
      __syncthreads();                              // barrier 1: Ulds ready

      // ---- GEMM1: [16,512] @ W1-slice ----
      f32x4 acc1_0 = {0.f, 0.f, 0.f, 0.f}, acc1_1 = {0.f, 0.f, 0.f, 0.f};
      {
        const int abase = lr * LDU + lk * 8;
        #pragma unroll
        for (int kt = 0; kt < 16; ++kt) {
          short8 a = *(const short8*)&Ulds[abase + kt * 32];
          acc1_0 = __builtin_amdgcn_mfma_f32_16x16x32_bf16(a, w1f[0][kt], acc1_0, 0, 0, 0);
          acc1_1 = __builtin_amdgcn_mfma_f32_16x16x32_bf16(a, w1f[1][kt], acc1_1, 0, 0, 0);
        }
      }
      #pragma unroll
      for (int n = 0; n < 2; ++n) {
        f32x4 a = n ? acc1_1 : acc1_0;
        #pragma unroll
        for (int q = 0; q < 4; ++q)
          Zlds[(lk * 4 + q) * LDZ + wv * 32 + n * 16 + lr] = f2bf(fast_tanh(a[q] + b1c[n]));
      }
      __syncthreads();                              // barrier 2: Zlds ready

      // ---- export Z as tagged words (fire-and-forget, no drain/flag) ----
      {
        const unsigned long long tz = (unsigned long long)(unsigned)(j + 1) << 32;
        unsigned long long* zb = &ZD[(((size_t)g * 16 + il) * 16) * 64];
        #pragma unroll
        for (int u = 0; u < 4; ++u) {
          int W = tid + u * 256;                    // 0..1023
          int zrow = W >> 6, cp = W & 63;           // row, col-pair
          unsigned zpair = *(const unsigned*)&Zlds[zrow * LDZ + cp * 2];
          sta64(zb + zrow * 64 + cp, (unsigned long long)zpair | tz);
        }
      }

      // ---- GEMM2: per-member tag-gated consume (wave wv: members wv*4+q) ----
      f32x4 acc2_0 = {0.f, 0.f, 0.f, 0.f}, acc2_1 = {0.f, 0.f, 0.f, 0.f};
      {
        const unsigned zt = (unsigned)(j + 1);
        #pragma unroll
        for (int q = 0; q < 4; ++q) {
          const int m = wv * 4 + q;
          const unsigned long long* zw =
              &ZD[(((size_t)g * 16 + m) * 16 + lr) * 64 + lk * 4];
          unsigned long long w[16];
          for (;;) {
            #pragma unroll
            for (int k2 = 0; k2 < 4; ++k2)
              #pragma unroll
              for (int i = 0; i < 4; ++i)
                w[k2 * 4 + i] = lda64(zw + k2 * 16 + i);
            bool ok = true;
            #pragma unroll
            for (int i = 0; i < 16; ++i) ok &= ((unsigned)(w[i] >> 32) == zt);
            if (__all((int)ok)) break;
            __builtin_amdgcn_s_sleep(1);
          }
          #pragma unroll
          for (int k2 = 0; k2 < 4; ++k2) {
            u32x4 pw = {(unsigned)w[k2 * 4 + 0], (unsigned)w[k2 * 4 + 1],
                        (unsigned)w[k2 * 4 + 2], (unsigned)w[k2 * 4 + 3]};
            short8 az = __builtin_bit_cast(short8, pw);
            const int kt = q * 4 + k2;
            acc2_0 = __builtin_amdgcn_mfma_f32_16x16x32_bf16(az, w2f[0][kt], acc2_0, 0, 0, 0);
            acc2_1 = __builtin_amdgcn_mfma_f32_16x16x32_bf16(az, w2f[1][kt], acc2_1, 0, 0, 0);
          }
        }
      }
      // ---- deterministic cross-wave reduce ----
      #pragma unroll
      for (int q = 0; q < 4; ++q) {
        red[wv][lk * 4 + q][lr]      = acc2_0[q];
        red[wv][lk * 4 + q][16 + lr] = acc2_1[q];
      }
      __syncthreads();                              // barrier 3: partials in LDS
      {
        float s0 = red[0][rowe][c2] + red[1][rowe][c2] + red[2][rowe][c2] + red[3][rowe][c2] + b2e0;
        float s1 = red[0][rowe][c2 + 1] + red[1][rowe][c2 + 1] + red[2][rowe][c2 + 1] + red[3][rowe][c2 + 1] + b2e1;
        const unsigned tk = (unsigned)(j + 1);
        unsigned long long* kb = &kD[((size_t)g * 16 + rowe) * 512 + il * 32 + c2];
        sta64(kb,     tagf32(s0, tk));
        sta64(kb + 1, tagf32(s1, tk));
      }
      ++j;
    }
  }

  // ---------- epilogue: final y-update + y_t[:, 63, :] ----------
  {
    const unsigned tgt = (unsigned)j;               // j == 252
    unsigned long long w[32];
    for (;;) {
      #pragma unroll
      for (int i = 0; i < 32; ++i) w[i] = lda64(myK + i);
      bool ok = true;
      #pragma unroll
      for (int i = 0; i < 32; ++i) ok &= ((unsigned)(w[i] >> 32) == tgt);
      if (__all((int)ok)) break;
      __builtin_amdgcn_s_sleep(1);
    }
    const float hp6 = (te[Td - 1] - te[Td - 2]) * (1.0f / 6.0f);
    #pragma unroll
    for (int p2 = 0; p2 < 32; ++p2)
      yv[p2] += hp6 * (acc_y[p2] + __builtin_bit_cast(float, (unsigned)w[p2]));
    if (cq == il) {
      #pragma unroll
      for (int gg = 0; gg < 8; ++gg) {
        f32x4 v = {yv[gg * 4], yv[gg * 4 + 1], yv[gg * 4 + 2], yv[gg * 4 + 3]};
        *(f32x4*)&out[rowg * (Td * Nd) + (Td - 1) * Nd + cb + gg * 4] = v;
      }
    }
  }
}

extern "C" void kernel_launch(void* const* d_in, const int* in_sizes, int n_in,
                              void* d_out, int out_size, void* d_ws, size_t ws_size,
                              hipStream_t stream) {
  const float* y0 = (const float*)d_in[0];
  const float* te = (const float*)d_in[1];
  const float* W1 = (const float*)d_in[2];
  const float* b1 = (const float*)d_in[3];
  const float* W2 = (const float*)d_in[4];
  const float* b2 = (const float*)d_in[5];
  float* out = (float*)d_out;

  char* p = (char*)d_ws;
  unsigned long long* kD = (unsigned long long*)p;                   // 1 MB tagged k
  unsigned long long* ZD = (unsigned long long*)(p + (1 << 20));     // 2 MB tagged Z

  // zero tags each launch (graph-replay determinism: tags restart at 0)
  hipMemsetAsync(d_ws, 0, 3 << 20, stream);
  ode_tg<<<dim3(256), dim3(256), 0, stream>>>(y0, te, W1, b1, W2, b2, out, kD, ZD);
}

// Round 13
// 5300.893 us; speedup vs baseline: 1.0897x; 1.0897x over previous
//
#include <hip/hip_runtime.h>
#include <hip/hip_bf16.h>

#define Bsz 256
#define Nd  512
#define Hd  2048
#define Td  64
#define OFF_T (Bsz * Td * Nd)
#define OFF_L (OFF_T + Td)
#define LDU 514   // Ulds stride (elements)
#define LDZ 68    // Zlds stride (64 cols + pad, keeps u64 reads 8B-aligned)

typedef __attribute__((ext_vector_type(8))) short short8;
typedef __attribute__((ext_vector_type(4))) float f32x4;

static __device__ __forceinline__ unsigned short f2bf(float x) {
  unsigned u = __builtin_bit_cast(unsigned, x);
  u += 0x7FFFu + ((u >> 16) & 1u);   // RNE
  return (unsigned short)(u >> 16);
}
static __device__ __forceinline__ float fast_tanh(float x) {
  float ex = __expf(2.0f * x);       // inf-safe
  return 1.0f - 2.0f / (ex + 1.0f);
}
// ---- agent-scope (sc1, LLC) primitives — the ONLY verified cross-block path ----
static __device__ __forceinline__ unsigned long long lda64(const void* p) {
  return __hip_atomic_load((const unsigned long long*)p, __ATOMIC_RELAXED,
                           __HIP_MEMORY_SCOPE_AGENT);
}
static __device__ __forceinline__ void sta64(void* p, unsigned long long v) {
  __hip_atomic_store((unsigned long long*)p, v, __ATOMIC_RELAXED,
                     __HIP_MEMORY_SCOPE_AGENT);
}
static __device__ __forceinline__ unsigned lda32(const unsigned* p) {
  return __hip_atomic_load(p, __ATOMIC_RELAXED, __HIP_MEMORY_SCOPE_AGENT);
}
static __device__ __forceinline__ void sta32(unsigned* p, unsigned v) {
  __hip_atomic_store(p, v, __ATOMIC_RELAXED, __HIP_MEMORY_SCOPE_AGENT);
}
// all-wave poll of a pod's 32-flag line (lane l covers flag l&31)
static __device__ __forceinline__ void pollf(const unsigned* f, unsigned tgt) {
  const unsigned* p = f + (threadIdx.x & 31);
  while (!__all((int)(lda32(p) >= tgt)))
    __builtin_amdgcn_s_sleep(1);
}

// 256 blocks x 256 threads (4 waves), 1 block/CU (LDS-forced).
// pod g = blk & 7 (32 members, rows g*32..g*32+32 = chains A,B of 16);
// member il = blk >> 3: H-slice cols il*64 (GEMM1) / N-slice cols il*16 (GEMM2).
// Two independent RK4 chains pipelined in anti-phase: each exchange's latency
// is hidden under the other chain's compute; flag posts piggyback on the
// vmcnt(0)-draining __syncthreads (r6-proven ordering).
__launch_bounds__(256, 1)
__global__ void ode_pl(const float* __restrict__ y0g, const float* __restrict__ te,
                       const float* __restrict__ W1, const float* __restrict__ b1,
                       const float* __restrict__ W2, const float* __restrict__ b2,
                       float* __restrict__ out, unsigned* __restrict__ flagZ,
                       unsigned* __restrict__ flagK,
                       float* __restrict__ kX, unsigned short* __restrict__ ZX) {
  __shared__ unsigned short Ulds[16 * LDU];
  __shared__ unsigned short Zlds[16 * LDZ];
  __shared__ float red[2][4][16][17];
  __shared__ char spad[54 * 1024];   // occupancy limiter: 1 block/CU

  const int blk = blockIdx.x;
  const int g = blk & 7, il = blk >> 3;
  const int tid = threadIdx.x;
  const int wv = tid >> 6, lane = tid & 63;
  const int lr = lane & 15, lk = lane >> 4;

  if (te[0] == 1.0e30f) {            // never true; keeps spad allocated
    ((volatile char*)spad)[tid] = (char)tid;
    out[0] = ((volatile char*)spad)[0];
  }

  // ---------- one-time: resident weight fragments ----------
  short8 w1f[16];                    // W1 B-frags: col = il*64 + wv*16 + lr
  {
    const int col = il * 64 + wv * 16 + lr;
    #pragma unroll
    for (int kt = 0; kt < 16; ++kt) {
      short8 v;
      #pragma unroll
      for (int jj = 0; jj < 8; ++jj)
        v[jj] = (short)f2bf(W1[(kt * 32 + lk * 8 + jj) * Hd + col]);
      w1f[kt] = v;
    }
  }
  short8 w2f[16];                    // W2 B-frags: col = il*16 + lr, K-chunk wv*512
  {
    const int col = il * 16 + lr;
    #pragma unroll
    for (int kt = 0; kt < 16; ++kt) {
      short8 v;
      #pragma unroll
      for (int jj = 0; jj < 8; ++jj)
        v[jj] = (short)f2bf(W2[(wv * 512 + kt * 32 + lk * 8 + jj) * Nd + col]);
      w2f[kt] = v;
    }
  }
  const float b1c = b1[il * 64 + wv * 16 + lr];
  const float b2e = b2[il * 16 + (tid & 15)];

  // ---------- per-thread state mapping ----------
  const int r  = tid >> 4;           // local row 0..15
  const int cq = tid & 15;           // 32-col N chunk
  const int cb = cq * 32;
  const int rowA = g * 32 + r;
  const int rowB = g * 32 + 16 + r;

  float yvA[32], yvB[32], accA[32], accB[32];
  #pragma unroll
  for (int gg = 0; gg < 8; ++gg) {
    f32x4 va = *(const f32x4*)&y0g[rowA * Nd + cb + gg * 4];
    f32x4 vb = *(const f32x4*)&y0g[rowB * Nd + cb + gg * 4];
    #pragma unroll
    for (int q = 0; q < 4; ++q) { yvA[gg * 4 + q] = va[q]; yvB[gg * 4 + q] = vb[q]; }
  }
  #pragma unroll
  for (int p = 0; p < 32; ++p) { accA[p] = 0.0f; accB[p] = 0.0f; }

  // ---------- pre-loop outputs ----------
  if (il == cq) {
    #pragma unroll
    for (int gg = 0; gg < 8; ++gg) {
      f32x4 va = {yvA[gg * 4], yvA[gg * 4 + 1], yvA[gg * 4 + 2], yvA[gg * 4 + 3]};
      *(f32x4*)&out[rowA * (Td * Nd) + cb + gg * 4] = va;
      f32x4 vb = {yvB[gg * 4], yvB[gg * 4 + 1], yvB[gg * 4 + 2], yvB[gg * 4 + 3]};
      *(f32x4*)&out[rowB * (Td * Nd) + cb + gg * 4] = vb;
    }
  }
  if (blk == 0) {
    if (tid < Td) out[OFF_T + tid] = te[tid];
    out[OFF_L + tid] = 0.0f;
  }

  unsigned* fZA = flagZ + g * 32;
  unsigned* fZB = flagZ + (8 + g) * 32;
  unsigned* fKA = flagK + g * 32;
  unsigned* fKB = flagK + (8 + g) * 32;
  float* kXA = kX;
  float* kXB = kX + (size_t)8 * 16 * 512;
  unsigned short* ZXA = ZX;
  unsigned short* ZXB = ZX + (size_t)8 * 32 * 16 * 64;
  const float* myKA = kXA + ((size_t)g * 16 + r) * 512 + cb;
  const float* myKB = kXB + ((size_t)g * 16 + r) * 512 + cb;

#define LOADKV(KV, SRC)                                                      \
  { _Pragma("unroll")                                                        \
    for (int p2 = 0; p2 < 16; ++p2) {                                        \
      unsigned long long q_ = lda64((SRC) + p2 * 2);                         \
      KV[2 * p2]     = __builtin_bit_cast(float, (unsigned)(q_ & 0xFFFFFFFFull)); \
      KV[2 * p2 + 1] = __builtin_bit_cast(float, (unsigned)(q_ >> 32));      \
    } }

#define UPHASE(YV, ACC, ROWG, KV)                                            \
  do {                                                                       \
    if (e == 1) {                                                            \
      if (t > 0) {                                                           \
        const float hp6_ = (te[t] - te[t - 1]) * (1.0f / 6.0f);              \
        _Pragma("unroll")                                                    \
        for (int p2 = 0; p2 < 32; ++p2) YV[p2] += hp6_ * (ACC[p2] + KV[p2]); \
        if (il == cq) {                                                      \
          _Pragma("unroll")                                                  \
          for (int gg = 0; gg < 8; ++gg) {                                   \
            f32x4 v_ = {YV[gg*4], YV[gg*4+1], YV[gg*4+2], YV[gg*4+3]};       \
            *(f32x4*)&out[(ROWG) * (Td * Nd) + t * Nd + cb + gg * 4] = v_;   \
          }                                                                  \
        }                                                                    \
      }                                                                      \
      _Pragma("unroll")                                                      \
      for (int p2 = 0; p2 < 32; ++p2) ACC[p2] = 0.0f;                        \
      _Pragma("unroll")                                                      \
      for (int gg = 0; gg < 4; ++gg) {                                       \
        short8 s_;                                                           \
        _Pragma("unroll")                                                    \
        for (int p2 = 0; p2 < 8; ++p2) s_[p2] = (short)f2bf(YV[gg * 8 + p2]);\
        *(short8*)&Ulds[r * LDU + cb + gg * 8] = s_;                         \
      }                                                                      \
    } else {                                                                 \
      const float cc_ = (e == 4) ? h : 0.5f * h;                             \
      const float ww_ = (e == 2) ? 1.0f : 2.0f;                              \
      _Pragma("unroll")                                                      \
      for (int gg = 0; gg < 4; ++gg) {                                       \
        short8 s_;                                                           \
        _Pragma("unroll")                                                    \
        for (int p2 = 0; p2 < 8; ++p2) {                                     \
          const int idx_ = gg * 8 + p2;                                      \
          ACC[idx_] += ww_ * KV[idx_];                                       \
          s_[p2] = (short)f2bf(YV[idx_] + cc_ * KV[idx_]);                   \
        }                                                                    \
        *(short8*)&Ulds[r * LDU + cb + gg * 8] = s_;                         \
      }                                                                      \
    }                                                                        \
  } while (0)

#define GEMM1()                                                              \
  { f32x4 a1_ = {0.f, 0.f, 0.f, 0.f};                                        \
    const int abase_ = lr * LDU + lk * 8;                                    \
    _Pragma("unroll")                                                        \
    for (int kt = 0; kt < 16; ++kt) {                                        \
      short8 a_ = *(const short8*)&Ulds[abase_ + kt * 32];                   \
      a1_ = __builtin_amdgcn_mfma_f32_16x16x32_bf16(a_, w1f[kt], a1_, 0,0,0);\
    }                                                                        \
    _Pragma("unroll")                                                        \
    for (int q = 0; q < 4; ++q)                                              \
      Zlds[(lk * 4 + q) * LDZ + wv * 16 + lr] = f2bf(fast_tanh(a1_[q] + b1c)); }

#define EXPORTZ(ZC)                                                          \
  { unsigned long long v_ =                                                  \
        *(const unsigned long long*)&Zlds[(tid >> 4) * LDZ + (tid & 15) * 4];\
    sta64(&(ZC)[((size_t)(g * 32 + il) * 16 + (tid >> 4)) * 64 + (tid & 15) * 4], v_); }

#define GEMM2(ZC, RC)                                                        \
  { f32x4 a2_ = {0.f, 0.f, 0.f, 0.f};                                        \
    _Pragma("unroll")                                                        \
    for (int kt = 0; kt < 16; ++kt) {                                        \
      const int m_ = wv * 8 + (kt >> 1);                                     \
      const unsigned short* zp_ =                                            \
          (ZC) + ((size_t)(g * 32 + m_) * 16 + lr) * 64 + (kt & 1) * 32 + lk * 8; \
      union { unsigned long long q2[2]; short8 s; } az_;                     \
      az_.q2[0] = lda64(zp_); az_.q2[1] = lda64(zp_ + 4);                    \
      a2_ = __builtin_amdgcn_mfma_f32_16x16x32_bf16(az_.s, w2f[kt], a2_, 0,0,0); \
    }                                                                        \
    _Pragma("unroll")                                                        \
    for (int q = 0; q < 4; ++q) red[RC][wv][lk * 4 + q][lr] = a2_[q]; }

#define SUMEXPK(RC, KC)                                                      \
  { const int kr_ = tid >> 4, kc_ = tid & 15;                                \
    float s_ = red[RC][0][kr_][kc_] + red[RC][1][kr_][kc_]                   \
             + red[RC][2][kr_][kc_] + red[RC][3][kr_][kc_] + b2e;            \
    sta32((unsigned*)&(KC)[((size_t)g * 16 + kr_) * 512 + il * 16 + kc_],    \
          __builtin_bit_cast(unsigned, s_)); }

  // ---------- main loop: 63 steps x 4 evals, 2 chains pipelined ----------
  int j = 0;
  for (int t = 0; t < Td - 1; ++t) {
    const float h = te[t + 1] - te[t];
    for (int e = 1; e <= 4; ++e) {
      float kv[32];
      // ===== Phase 1A: U+GEMM1 chain A =====
      if (!(e == 1 && t == 0)) { pollf(fKA, (unsigned)j); LOADKV(kv, myKA); }
      UPHASE(yvA, accA, rowA, kv);
      __syncthreads();                       // sync1: Ulds ready; drains exportK_B(prev)
      if (tid == 0 && j > 0) sta32(&fKB[il], (unsigned)j);
      GEMM1();
      __syncthreads();                       // sync2: Zlds(A) ready
      EXPORTZ(ZXA);                          // issue only
      // ===== Phase 1B: U+GEMM1 chain B =====
      if (!(e == 1 && t == 0)) { pollf(fKB, (unsigned)j); LOADKV(kv, myKB); }
      UPHASE(yvB, accB, rowB, kv);
      __syncthreads();                       // sync3: Ulds(B) ready; drains Z_A stores
      if (tid == 0) sta32(&fZA[il], (unsigned)(j + 1));
      GEMM1();
      __syncthreads();                       // sync4: Zlds(B) ready
      EXPORTZ(ZXB);                          // issue only
      // ===== Phase 2A: GEMM2 chain A =====
      pollf(fZA, (unsigned)(j + 1));
      GEMM2(ZXA, 0);
      __syncthreads();                       // sync5: red[0] ready; drains Z_B stores
      if (tid == 0) sta32(&fZB[il], (unsigned)(j + 1));
      SUMEXPK(0, kXA);                       // issue only
      // ===== Phase 2B: GEMM2 chain B =====
      pollf(fZB, (unsigned)(j + 1));
      GEMM2(ZXB, 1);
      __syncthreads();                       // sync6: red[1] ready; drains K_A stores
      if (tid == 0) sta32(&fKA[il], (unsigned)(j + 1));
      SUMEXPK(1, kXB);                       // issue only (drained at next sync1)
      ++j;
    }
  }

  // ---------- epilogue: final y-update + y_t[:, 63, :] (both chains) ----------
  __syncthreads();                           // drains exportK_B of last eval
  if (tid == 0) sta32(&fKB[il], (unsigned)j);    // j == 252
  {
    const float hp6 = (te[Td - 1] - te[Td - 2]) * (1.0f / 6.0f);
    float kv[32];
    pollf(fKA, (unsigned)j);
    LOADKV(kv, myKA);
    #pragma unroll
    for (int p2 = 0; p2 < 32; ++p2) yvA[p2] += hp6 * (accA[p2] + kv[p2]);
    pollf(fKB, (unsigned)j);
    LOADKV(kv, myKB);
    #pragma unroll
    for (int p2 = 0; p2 < 32; ++p2) yvB[p2] += hp6 * (accB[p2] + kv[p2]);
    if (il == cq) {
      #pragma unroll
      for (int gg = 0; gg < 8; ++gg) {
        f32x4 va = {yvA[gg * 4], yvA[gg * 4 + 1], yvA[gg * 4 + 2], yvA[gg * 4 + 3]};
        *(f32x4*)&out[rowA * (Td * Nd) + (Td - 1) * Nd + cb + gg * 4] = va;
        f32x4 vb = {yvB[gg * 4], yvB[gg * 4 + 1], yvB[gg * 4 + 2], yvB[gg * 4 + 3]};
        *(f32x4*)&out[rowB * (Td * Nd) + (Td - 1) * Nd + cb + gg * 4] = vb;
      }
    }
  }
}

extern "C" void kernel_launch(void* const* d_in, const int* in_sizes, int n_in,
                              void* d_out, int out_size, void* d_ws, size_t ws_size,
                              hipStream_t stream) {
  const float* y0 = (const float*)d_in[0];
  const float* te = (const float*)d_in[1];
  const float* W1 = (const float*)d_in[2];
  const float* b1 = (const float*)d_in[3];
  const float* W2 = (const float*)d_in[4];
  const float* b2 = (const float*)d_in[5];
  float* out = (float*)d_out;

  char* p = (char*)d_ws;
  unsigned* flagZ = (unsigned*)p;                 // 2 KB: 2 chains x 8 pods x 32
  unsigned* flagK = (unsigned*)(p + 2048);        // 2 KB
  float* kX = (float*)(p + 4096);                 // 512 KB: 2 x [8][16][512] f32
  unsigned short* ZX = (unsigned short*)(p + 4096 + 512 * 1024);  // 1 MB: 2 x [8][32][16][64] bf16

  hipMemsetAsync(d_ws, 0, 4096, stream);          // zero all flags each launch
  ode_pl<<<dim3(256), dim3(256), 0, stream>>>(y0, te, W1, b1, W2, b2, out,
                                              flagZ, flagK, kX, ZX);
}